// Round 3
// baseline (70.103 us; speedup 1.0000x reference)
//
#include <hip/hip_runtime.h>

// PIT loss: x,y [B=8, C=4, CH=2, T=262144] f32. D = CH*T = 524288.
// dists[b,i,j] = (sum(y[b,i]^2) + sum(x[b,j]^2) - 2*sum(x[b,j]*y[b,i])) / D
// total = sum_b min_p sum_i dists[b,i,perm[p][i]]; assignments[b] = argmin perm.
//
// Single fused kernel: grid-wide reduction into ws partials, last-arriving
// block (device-scope atomic + threadfence, per G16/G12) does the 24-perm
// assignment + total. Counter is zeroed via hipMemsetAsync before launch.

#define BATCH   8
#define CDIM    4
#define DLEN    (2 * 262144)        // 524288 scalars per (b, c)
#define F4_PER_C (DLEN / 4)         // 131072 float4 per channel
#define BPB     64                  // blocks per batch (round-1 best replay shape)
#define TPB     256
#define NVAL    24                  // 4 sx + 4 sy + 16 cross
#define NBLOCKS (BATCH * BPB)       // 512

// itertools.permutations(range(4)) lexicographic order
__device__ __constant__ int PERMS[24][4] = {
    {0,1,2,3},{0,1,3,2},{0,2,1,3},{0,2,3,1},{0,3,1,2},{0,3,2,1},
    {1,0,2,3},{1,0,3,2},{1,2,0,3},{1,2,3,0},{1,3,0,2},{1,3,2,0},
    {2,0,1,3},{2,0,3,1},{2,1,0,3},{2,1,3,0},{2,3,0,1},{2,3,1,0},
    {3,0,1,2},{3,0,2,1},{3,1,0,2},{3,1,2,0},{3,2,0,1},{3,2,1,0}
};

__global__ __launch_bounds__(TPB) void pit_fused(const float* __restrict__ x,
                                                 const float* __restrict__ y,
                                                 float* __restrict__ ws,
                                                 unsigned int* __restrict__ counter,
                                                 float* __restrict__ out) {
    const int b   = blockIdx.x / BPB;
    const int blk = blockIdx.x % BPB;
    const int tid = threadIdx.x;

    const int f4_per_block = F4_PER_C / BPB;     // 2048
    const int iters        = f4_per_block / TPB; // 8
    const int base_f4      = blk * f4_per_block;

    const float4* __restrict__ xb = (const float4*)(x + (size_t)b * CDIM * DLEN);
    const float4* __restrict__ yb = (const float4*)(y + (size_t)b * CDIM * DLEN);

    float sx[4] = {0.f, 0.f, 0.f, 0.f};
    float sy[4] = {0.f, 0.f, 0.f, 0.f};
    float cr[4][4] = {};

    for (int it = 0; it < iters; ++it) {
        const int p = base_f4 + it * TPB + tid;
        float4 xv[4], yv[4];
#pragma unroll
        for (int c = 0; c < 4; ++c) xv[c] = xb[(size_t)c * F4_PER_C + p];
#pragma unroll
        for (int c = 0; c < 4; ++c) yv[c] = yb[(size_t)c * F4_PER_C + p];
#pragma unroll
        for (int c = 0; c < 4; ++c) {
            sx[c] += xv[c].x * xv[c].x + xv[c].y * xv[c].y +
                     xv[c].z * xv[c].z + xv[c].w * xv[c].w;
            sy[c] += yv[c].x * yv[c].x + yv[c].y * yv[c].y +
                     yv[c].z * yv[c].z + yv[c].w * yv[c].w;
        }
#pragma unroll
        for (int i = 0; i < 4; ++i)
#pragma unroll
            for (int j = 0; j < 4; ++j)
                cr[i][j] += yv[i].x * xv[j].x + yv[i].y * xv[j].y +
                            yv[i].z * xv[j].z + yv[i].w * xv[j].w;
    }

    // pack 24 accumulators: [0..3]=sx, [4..7]=sy, [8..23]=cr[i][j]
    float v[NVAL];
#pragma unroll
    for (int c = 0; c < 4; ++c) { v[c] = sx[c]; v[4 + c] = sy[c]; }
#pragma unroll
    for (int i = 0; i < 4; ++i)
#pragma unroll
        for (int j = 0; j < 4; ++j) v[8 + i * 4 + j] = cr[i][j];

    // wave64 tree reduce (deterministic)
#pragma unroll
    for (int k = 0; k < NVAL; ++k) {
#pragma unroll
        for (int off = 32; off > 0; off >>= 1)
            v[k] += __shfl_down(v[k], off);
    }

    __shared__ float red[4][NVAL];
    const int wave = tid >> 6, lane = tid & 63;
    if (lane == 0) {
#pragma unroll
        for (int k = 0; k < NVAL; ++k) red[wave][k] = v[k];
    }
    __syncthreads();
    if (tid < NVAL) {
        float s = red[0][tid] + red[1][tid] + red[2][tid] + red[3][tid];
        ws[(size_t)(b * BPB + blk) * NVAL + tid] = s;
    }

    // ---- grid-wide completion: elect the last block (device scope) ----
    __shared__ int is_last;
    __threadfence();                 // release ws writes device-wide
    if (tid == 0) {
        unsigned int prev = atomicAdd(counter, 1u);   // device-scope by default
        is_last = (prev == NBLOCKS - 1) ? 1 : 0;
    }
    __syncthreads();
    if (!is_last) return;
    __threadfence();                 // acquire: order subsequent ws reads

    // ---- finalize (one block, 256 threads) ----
    __shared__ double stage[BATCH][NVAL];
    __shared__ double dists[BATCH][4][4];
    __shared__ double mins[BATCH];

    if (tid < BATCH * NVAL) {        // 192 threads
        const int bb = tid / NVAL, k = tid % NVAL;
        double s0 = 0.0, s1 = 0.0, s2 = 0.0, s3 = 0.0;
        for (int q = 0; q < BPB; q += 4) {
            s0 += (double)ws[(size_t)(bb * BPB + q + 0) * NVAL + k];
            s1 += (double)ws[(size_t)(bb * BPB + q + 1) * NVAL + k];
            s2 += (double)ws[(size_t)(bb * BPB + q + 2) * NVAL + k];
            s3 += (double)ws[(size_t)(bb * BPB + q + 3) * NVAL + k];
        }
        stage[bb][k] = (s0 + s1) + (s2 + s3);
    }
    __syncthreads();

    if (tid < BATCH * 16) {          // 128 threads
        const int bb = tid / 16, ij = tid % 16, i = ij / 4, j = ij % 4;
        dists[bb][i][j] = (stage[bb][4 + i] + stage[bb][j]
                           - 2.0 * stage[bb][8 + i * 4 + j]) / (double)DLEN;
    }
    __syncthreads();

    if (tid < BATCH) {
        const int bb = tid;
        double best = 1e300;
        int bestp = 0;
        for (int p = 0; p < 24; ++p) {
            double c = 0.0;
#pragma unroll
            for (int i = 0; i < 4; ++i) c += dists[bb][i][PERMS[p][i]];
            if (c < best) { best = c; bestp = p; }   // strict < => first min (jnp.argmin)
        }
        mins[bb] = best;
#pragma unroll
        for (int i = 0; i < 4; ++i)
            out[1 + bb * 4 + i] = (float)PERMS[bestp][i];
    }
    __syncthreads();

    if (tid == 0) {
        double tot = 0.0;
        for (int bb = 0; bb < BATCH; ++bb) tot += mins[bb];
        out[0] = (float)tot;
    }
}

extern "C" void kernel_launch(void* const* d_in, const int* in_sizes, int n_in,
                              void* d_out, int out_size, void* d_ws, size_t ws_size,
                              hipStream_t stream) {
    const float* x = (const float*)d_in[0];
    const float* y = (const float*)d_in[1];
    float* out = (float*)d_out;
    float* ws  = (float*)d_ws;

    // ws layout: [0, NBLOCKS*NVAL) float partials (48 KiB), then counter.
    unsigned int* counter = (unsigned int*)(ws + NBLOCKS * NVAL);

    hipMemsetAsync(counter, 0, sizeof(unsigned int), stream);  // async: capture-safe
    pit_fused<<<NBLOCKS, TPB, 0, stream>>>(x, y, ws, counter, out);
}

// Round 4
// 32.684 us; speedup vs baseline: 2.1449x; 2.1449x over previous
//
#include <hip/hip_runtime.h>

// PIT loss: x,y [B=8, C=4, CH=2, T=262144] f32. D = CH*T = 524288.
// dists[b,i,j] = (sum(y[b,i]^2) + sum(x[b,j]^2) - 2*sum(x[b,j]*y[b,i])) / D
// total = sum_b min_p sum_i dists[b,i,perm[p][i]]; assignments[b] = argmin perm.
//
// Two kernels (fused last-block variant regressed 2x: per-block device-scope
// fence = L2 writeback per block on non-coherent XCDs). ws is transposed to
// [k][block] so the finalize reads one contiguous 48 KiB span coalesced.

#define BATCH   8
#define CDIM    4
#define DLEN    (2 * 262144)        // 524288 scalars per (b, c)
#define F4_PER_C (DLEN / 4)         // 131072 float4 per channel
#define BPB     64                  // blocks per batch (best replay shape, R1)
#define TPB     256
#define NVAL    24                  // 4 sx + 4 sy + 16 cross
#define NBLOCKS (BATCH * BPB)       // 512

// itertools.permutations(range(4)) lexicographic order
__device__ __constant__ int PERMS[24][4] = {
    {0,1,2,3},{0,1,3,2},{0,2,1,3},{0,2,3,1},{0,3,1,2},{0,3,2,1},
    {1,0,2,3},{1,0,3,2},{1,2,0,3},{1,2,3,0},{1,3,0,2},{1,3,2,0},
    {2,0,1,3},{2,0,3,1},{2,1,0,3},{2,1,3,0},{2,3,0,1},{2,3,1,0},
    {3,0,1,2},{3,0,2,1},{3,1,0,2},{3,1,2,0},{3,2,0,1},{3,2,1,0}
};

__global__ __launch_bounds__(TPB) void pit_reduce(const float* __restrict__ x,
                                                  const float* __restrict__ y,
                                                  float* __restrict__ ws) {
    const int b   = blockIdx.x / BPB;
    const int blk = blockIdx.x % BPB;
    const int tid = threadIdx.x;

    const int f4_per_block = F4_PER_C / BPB;     // 2048
    const int iters        = f4_per_block / TPB; // 8
    const int base_f4      = blk * f4_per_block;

    const float4* __restrict__ xb = (const float4*)(x + (size_t)b * CDIM * DLEN);
    const float4* __restrict__ yb = (const float4*)(y + (size_t)b * CDIM * DLEN);

    float sx[4] = {0.f, 0.f, 0.f, 0.f};
    float sy[4] = {0.f, 0.f, 0.f, 0.f};
    float cr[4][4] = {};

    for (int it = 0; it < iters; ++it) {
        const int p = base_f4 + it * TPB + tid;
        float4 xv[4], yv[4];
#pragma unroll
        for (int c = 0; c < 4; ++c) xv[c] = xb[(size_t)c * F4_PER_C + p];
#pragma unroll
        for (int c = 0; c < 4; ++c) yv[c] = yb[(size_t)c * F4_PER_C + p];
#pragma unroll
        for (int c = 0; c < 4; ++c) {
            sx[c] += xv[c].x * xv[c].x + xv[c].y * xv[c].y +
                     xv[c].z * xv[c].z + xv[c].w * xv[c].w;
            sy[c] += yv[c].x * yv[c].x + yv[c].y * yv[c].y +
                     yv[c].z * yv[c].z + yv[c].w * yv[c].w;
        }
#pragma unroll
        for (int i = 0; i < 4; ++i)
#pragma unroll
            for (int j = 0; j < 4; ++j)
                cr[i][j] += yv[i].x * xv[j].x + yv[i].y * xv[j].y +
                            yv[i].z * xv[j].z + yv[i].w * xv[j].w;
    }

    // pack 24 accumulators: [0..3]=sx, [4..7]=sy, [8..23]=cr[i][j]
    float v[NVAL];
#pragma unroll
    for (int c = 0; c < 4; ++c) { v[c] = sx[c]; v[4 + c] = sy[c]; }
#pragma unroll
    for (int i = 0; i < 4; ++i)
#pragma unroll
        for (int j = 0; j < 4; ++j) v[8 + i * 4 + j] = cr[i][j];

    // wave64 tree reduce (deterministic)
#pragma unroll
    for (int k = 0; k < NVAL; ++k) {
#pragma unroll
        for (int off = 32; off > 0; off >>= 1)
            v[k] += __shfl_down(v[k], off);
    }

    __shared__ float red[4][NVAL];
    const int wave = tid >> 6, lane = tid & 63;
    if (lane == 0) {
#pragma unroll
        for (int k = 0; k < NVAL; ++k) red[wave][k] = v[k];
    }
    __syncthreads();
    if (tid < NVAL) {
        float s = red[0][tid] + red[1][tid] + red[2][tid] + red[3][tid];
        // transposed: ws[k][global_block] -> contiguous per-k rows of 512 floats
        ws[(size_t)tid * NBLOCKS + (b * BPB + blk)] = s;
    }
}

__global__ __launch_bounds__(256) void pit_finalize(const float* __restrict__ ws,
                                                    float* __restrict__ out) {
    __shared__ double stage[BATCH][NVAL];   // summed partials
    __shared__ double dists[BATCH][4][4];
    __shared__ double mins[BATCH];
    const int tid = threadIdx.x;

    // 192 active threads, (k major, b minor): the whole block reads the
    // 48 KiB ws span fully coalesced as float4.
    if (tid < BATCH * NVAL) {
        const int k = tid / BATCH, bb = tid % BATCH;
        const float4* p = (const float4*)(ws + (size_t)k * NBLOCKS + bb * BPB);
        double s0 = 0.0, s1 = 0.0, s2 = 0.0, s3 = 0.0;
#pragma unroll
        for (int q = 0; q < 16; q += 4) {
            float4 a = p[q + 0], c = p[q + 1], d = p[q + 2], e = p[q + 3];
            s0 += (double)a.x + (double)a.y + (double)a.z + (double)a.w;
            s1 += (double)c.x + (double)c.y + (double)c.z + (double)c.w;
            s2 += (double)d.x + (double)d.y + (double)d.z + (double)d.w;
            s3 += (double)e.x + (double)e.y + (double)e.z + (double)e.w;
        }
        stage[bb][k] = (s0 + s1) + (s2 + s3);
    }
    __syncthreads();

    if (tid < BATCH * 16) {                 // 128 threads
        const int bb = tid / 16, ij = tid % 16, i = ij / 4, j = ij % 4;
        dists[bb][i][j] = (stage[bb][4 + i] + stage[bb][j]
                           - 2.0 * stage[bb][8 + i * 4 + j]) / (double)DLEN;
    }
    __syncthreads();

    if (tid < BATCH) {
        const int bb = tid;
        double best = 1e300;
        int bestp = 0;
        for (int p = 0; p < 24; ++p) {
            double c = 0.0;
#pragma unroll
            for (int i = 0; i < 4; ++i) c += dists[bb][i][PERMS[p][i]];
            if (c < best) { best = c; bestp = p; }   // strict < => first min (jnp.argmin)
        }
        mins[bb] = best;
#pragma unroll
        for (int i = 0; i < 4; ++i)
            out[1 + bb * 4 + i] = (float)PERMS[bestp][i];
    }
    __syncthreads();

    if (tid == 0) {
        double tot = 0.0;
        for (int bb = 0; bb < BATCH; ++bb) tot += mins[bb];
        out[0] = (float)tot;
    }
}

extern "C" void kernel_launch(void* const* d_in, const int* in_sizes, int n_in,
                              void* d_out, int out_size, void* d_ws, size_t ws_size,
                              hipStream_t stream) {
    const float* x = (const float*)d_in[0];
    const float* y = (const float*)d_in[1];
    float* out = (float*)d_out;
    float* ws  = (float*)d_ws;     // needs NVAL*NBLOCKS*4 = 49152 bytes

    pit_reduce<<<NBLOCKS, TPB, 0, stream>>>(x, y, ws);
    pit_finalize<<<1, 256, 0, stream>>>(ws, out);
}